// Round 14
// baseline (3507.389 us; speedup 1.0000x reference)
//
#include <hip/hip_runtime.h>
#include <hip/hip_fp16.h>

#define H 161
#define G4 644            // 4*H gates
#define BB 32             // batch
#define TT 1000           // time
#define M_TOT (BB*TT)     // 32000 rows
#define KXP 192           // padded K for pre GEMM (161 data + 1 bias + pad0)
#define KLP 352           // padded K for lin GEMM (322 data + pad0)
#define NWIH 1344         // padded N of wih16 (21 * 64)
#define NPAIR 84          // half2 pairs covering K padded to 168 (scan)
#define NVEC (NPAIR/4)    // 21 uint4 reads of the h vector (scan)

typedef _Float16 h2_t  __attribute__((ext_vector_type(2)));
typedef _Float16 f16x8 __attribute__((ext_vector_type(8)));
typedef float    f32x4 __attribute__((ext_vector_type(4)));

__device__ __forceinline__ h2_t bc_h2(unsigned int u) {
    return __builtin_bit_cast(h2_t, u);
}

__device__ __forceinline__ float dot2f(h2_t a, h2_t b, float c) {
#if __has_builtin(__builtin_amdgcn_fdot2)
    return __builtin_amdgcn_fdot2(a, b, c, false);
#else
    return c + (float)a[0] * (float)b[0] + (float)a[1] * (float)b[1];
#endif
}

__device__ __forceinline__ float tanh_f(float x) {
    return 1.0f - 2.0f / (__expf(2.0f * x) + 1.0f);
}

// Quad-perm DPP move (returns the permuted value). Pattern verified on this
// HW/compiler by round 2's qsum. All quad lanes are always active here.
template<int CTRL>
__device__ __forceinline__ float dpp_qp(float x) {
    int y = __builtin_amdgcn_update_dpp(0, __builtin_bit_cast(int, x),
                                        CTRL, 0xF, 0xF, true);
    return __builtin_bit_cast(float, y);
}

// Barrier draining only LDS (lgkmcnt), not vmcnt.
__device__ __forceinline__ void bar_lds() {
    __builtin_amdgcn_sched_barrier(0);
    asm volatile("s_waitcnt lgkmcnt(0)" ::: "memory");
    __builtin_amdgcn_s_barrier();
    __builtin_amdgcn_sched_barrier(0);
}

// ---------------------------------------------------------------------------
// cvt_x: layer-0 input only. Sets bias column (k=161 -> 1.0) and zero pad;
// lin_mfma's fused A16 write (layers 1,2) only touches k<161.
// ---------------------------------------------------------------------------
__global__ __launch_bounds__(256) void cvt_x(
    const float* __restrict__ in,    // [M][161] fp32
    __half* __restrict__ out)        // [M][192] fp16
{
    const int total = M_TOT * KXP;
    for (int idx = blockIdx.x * 256 + threadIdx.x; idx < total;
         idx += gridDim.x * 256) {
        int m = idx / KXP, k = idx - m * KXP;
        float v = (k < H) ? in[(size_t)m * H + k] : (k == H ? 1.f : 0.f);
        out[idx] = __float2half(v);
    }
}

// ---------------------------------------------------------------------------
// cvt_wih3 / cvt_W3: all three layers' weight conversions, one launch each.
// ---------------------------------------------------------------------------
__global__ __launch_bounds__(256) void cvt_wih3(
    const float* __restrict__ wf0, const float* __restrict__ wb0,
    const float* __restrict__ bif0, const float* __restrict__ bhf0,
    const float* __restrict__ bib0, const float* __restrict__ bhb0,
    const float* __restrict__ wf1, const float* __restrict__ wb1,
    const float* __restrict__ bif1, const float* __restrict__ bhf1,
    const float* __restrict__ bib1, const float* __restrict__ bhb1,
    const float* __restrict__ wf2, const float* __restrict__ wb2,
    const float* __restrict__ bif2, const float* __restrict__ bhf2,
    const float* __restrict__ bib2, const float* __restrict__ bhb2,
    __half* __restrict__ out)        // [3][1344][192] fp16
{
    const int l = blockIdx.y;
    const float* wf  = (l == 0) ? wf0  : (l == 1) ? wf1  : wf2;
    const float* wb  = (l == 0) ? wb0  : (l == 1) ? wb1  : wb2;
    const float* bif = (l == 0) ? bif0 : (l == 1) ? bif1 : bif2;
    const float* bhf = (l == 0) ? bhf0 : (l == 1) ? bhf1 : bhf2;
    const float* bib = (l == 0) ? bib0 : (l == 1) ? bib1 : bib2;
    const float* bhb = (l == 0) ? bhb0 : (l == 1) ? bhb1 : bhb2;
    __half* o = out + (size_t)l * NWIH * KXP;

    const int total = NWIH * KXP;
    for (int idx = blockIdx.x * 256 + threadIdx.x; idx < total;
         idx += gridDim.x * 256) {
        int n = idx / KXP, k = idx - n * KXP;
        float v = 0.f;
        if (n < G4) {
            v = (k < H) ? wf[(size_t)n * H + k]
                        : (k == H ? bif[n] + bhf[n] : 0.f);
        } else if (n < 2 * G4) {
            int g = n - G4;
            v = (k < H) ? wb[(size_t)g * H + k]
                        : (k == H ? bib[g] + bhb[g] : 0.f);
        }
        o[idx] = __float2half(v);
    }
}

__global__ __launch_bounds__(256) void cvt_W3(
    const float* __restrict__ W0, const float* __restrict__ W1,
    const float* __restrict__ W2,
    __half* __restrict__ out)        // [3][192][352] fp16
{
    const int l = blockIdx.y;
    const float* W = (l == 0) ? W0 : (l == 1) ? W1 : W2;
    __half* o = out + (size_t)l * 192 * KLP;

    const int total = 192 * KLP;
    for (int idx = blockIdx.x * 256 + threadIdx.x; idx < total;
         idx += gridDim.x * 256) {
        int n = idx / KLP, k = idx - n * KLP;
        float v = (n < H && k < 2 * H) ? W[(size_t)n * (2 * H) + k] : 0.f;
        o[idx] = __float2half(v);
    }
}

// ---------------------------------------------------------------------------
// pre_mfma (unchanged from round 13 -- verified, A-fragment reuse x3).
// ---------------------------------------------------------------------------
__global__ __launch_bounds__(256) void pre_mfma(
    const __half* __restrict__ A16,    // [M][192]
    const __half* __restrict__ Wih16,  // [1344][192] (one layer)
    __half* __restrict__ pre)          // [2][M_TOT][644]
{
    const int m0 = blockIdx.x * 64;
    const int n0b = blockIdx.y * 192;
    const int tid = threadIdx.x;
    const int wv = tid >> 6, l = tid & 63;
    const int wm = wv & 1, wn = wv >> 1;
    const int cl = l & 15, kg = l >> 4;

    const __half* ap = A16 + (size_t)(m0 + wm * 32 + cl) * KXP + kg * 8;
    f16x8 xa0[6], xa1[6];
    #pragma unroll
    for (int kt = 0; kt < 6; ++kt) {
        xa0[kt] = *(const f16x8*)(ap + kt * 32);
        xa1[kt] = *(const f16x8*)(ap + 16 * KXP + kt * 32);
    }

    for (int nb = 0; nb < 3; ++nb) {
        const int n0 = n0b + nb * 64;
        const __half* wp = Wih16 + (size_t)(n0 + wn * 32 + cl) * KXP + kg * 8;

        f32x4 acc[2][2] = {};
        #pragma unroll
        for (int kt = 0; kt < 6; ++kt) {
            f16x8 w0 = *(const f16x8*)(wp + kt * 32);
            f16x8 w1 = *(const f16x8*)(wp + 16 * KXP + kt * 32);
            acc[0][0] = __builtin_amdgcn_mfma_f32_16x16x32_f16(w0, xa0[kt], acc[0][0], 0, 0, 0);
            acc[0][1] = __builtin_amdgcn_mfma_f32_16x16x32_f16(w0, xa1[kt], acc[0][1], 0, 0, 0);
            acc[1][0] = __builtin_amdgcn_mfma_f32_16x16x32_f16(w1, xa0[kt], acc[1][0], 0, 0, 0);
            acc[1][1] = __builtin_amdgcn_mfma_f32_16x16x32_f16(w1, xa1[kt], acc[1][1], 0, 0, 0);
        }

        #pragma unroll
        for (int sn = 0; sn < 2; ++sn)
            #pragma unroll
            for (int sm = 0; sm < 2; ++sm) {
                int n = n0 + wn * 32 + sn * 16 + kg * 4;
                int m = m0 + wm * 32 + sm * 16 + cl;
                if (n < 2 * G4) {
                    int d = (n >= G4) ? 1 : 0;
                    int g = n - d * G4;
                    __half2 lo, hi;
                    lo.x = __float2half(acc[sn][sm][0]);
                    lo.y = __float2half(acc[sn][sm][1]);
                    hi.x = __float2half(acc[sn][sm][2]);
                    hi.y = __float2half(acc[sn][sm][3]);
                    __half* dst = pre + ((size_t)d * M_TOT + m) * G4 + g;
                    *(__half2*)dst = lo;
                    *(__half2*)(dst + 2) = hi;
                }
            }
    }
}

// ---------------------------------------------------------------------------
// lin_mfma (unchanged from round 13 -- verified, fused A16 write).
// ---------------------------------------------------------------------------
__global__ __launch_bounds__(256) void lin_mfma(
    const __half* __restrict__ Hc,     // [M][352] fp16
    const __half* __restrict__ W16,    // [192][352] (one layer)
    const float* __restrict__ bl,      // [161]
    const float* __restrict__ res,     // [M][161] fp32
    float* __restrict__ out,           // [M][161] fp32
    __half* __restrict__ A16out,       // [M][192] fp16 (next layer's A)
    int relu, int wr_a16)
{
    const int m0 = blockIdx.x * 64, n0 = blockIdx.y * 64;
    const int tid = threadIdx.x;
    const int wv = tid >> 6, l = tid & 63;
    const int wm = wv & 1, wn = wv >> 1;
    const int cl = l & 15, kg = l >> 4;

    const __half* ap = Hc  + (size_t)(m0 + wm * 32 + cl) * KLP + kg * 8;
    const __half* wp = W16 + (size_t)(n0 + wn * 32 + cl) * KLP + kg * 8;

    f32x4 acc[2][2] = {};
    #pragma unroll
    for (int kt = 0; kt < 11; ++kt) {
        f16x8 w0 = *(const f16x8*)(wp + kt * 32);
        f16x8 w1 = *(const f16x8*)(wp + 16 * KLP + kt * 32);
        f16x8 x0 = *(const f16x8*)(ap + kt * 32);
        f16x8 x1 = *(const f16x8*)(ap + 16 * KLP + kt * 32);
        acc[0][0] = __builtin_amdgcn_mfma_f32_16x16x32_f16(w0, x0, acc[0][0], 0, 0, 0);
        acc[0][1] = __builtin_amdgcn_mfma_f32_16x16x32_f16(w0, x1, acc[0][1], 0, 0, 0);
        acc[1][0] = __builtin_amdgcn_mfma_f32_16x16x32_f16(w1, x0, acc[1][0], 0, 0, 0);
        acc[1][1] = __builtin_amdgcn_mfma_f32_16x16x32_f16(w1, x1, acc[1][1], 0, 0, 0);
    }

    #pragma unroll
    for (int sn = 0; sn < 2; ++sn)
        #pragma unroll
        for (int sm = 0; sm < 2; ++sm) {
            int nb = n0 + wn * 32 + sn * 16 + kg * 4;
            int m  = m0 + wm * 32 + sm * 16 + cl;
            #pragma unroll
            for (int r = 0; r < 4; ++r) {
                int n = nb + r;
                if (n < H) {
                    float v = acc[sn][sm][r] + bl[n];
                    if (relu) v = fmaxf(v, 0.f);
                    v += res[(size_t)m * H + n];
                    out[(size_t)m * H + n] = v;
                    if (wr_a16)
                        A16out[(size_t)m * KXP + n] = __float2half(v);
                }
            }
        }
}

// ---------------------------------------------------------------------------
// lstm_scan v14 (quad-gate DPP): 704 threads = 11 waves, 1 gate row per lane
// exactly as the 995us R10 kernel, but the lane->gate mapping puts the four
// gates of each hid in ONE QUAD: lane l -> hid = wv*16 + (l>>2), gate = l&3.
// After the (unchanged) 84-dot2 loop + activation, three quad_perm DPPs
// deliver f,g,o to the gate-0 lane, which updates c and publishes h -- no
// gate_sh round-trip, no serialized 3-wave update phase, ONE lgkm-only
// barrier per step (h double-buffered; R2/R5-verified ordering).
// Targets the measured ~400-500 cyc/step tail; the 11-wave LDS h-broadcast
// (~1850 cyc/step) is the remaining floor (wave count can't drop: register
// wall measured in rounds 2,3,4,5,9,12).
// ---------------------------------------------------------------------------
__global__ __launch_bounds__(704, 3) void lstm_scan(
    const __half* __restrict__ pre,      // [2][M_TOT][G4] gate-major
    const float* __restrict__ whh_f,
    const float* __restrict__ whh_b,
    __half* __restrict__ hcat)           // [M_TOT][KLP] fp16
{
    const int b = blockIdx.x;            // 0..31
    const int d = blockIdx.y;            // 0,1
    const int tid = threadIdx.x;
    const int l = tid & 63, wv = tid >> 6;
    const int gate = l & 3;
    const int hid = wv * 16 + (l >> 2);          // 0..175
    const int hidc = (hid < H) ? hid : (H - 1);  // clamp pad lanes
    const bool writer = (gate == 0) && (hid < H);
    const bool is_g = (gate == 2);
    const float* whh = d ? whh_b : whh_f;

    __shared__ __align__(16) unsigned int h_sh[2][NPAIR];  // 2 x 168 halves

    // Weight row gate*H + hidc, packed half2, K padded to 168 (84 VGPRs --
    // same budget as the verified 995us kernel).
    h2_t w[NPAIR];
    {
        const float* row = whh + (size_t)(gate * H + hidc) * H;
        #pragma unroll
        for (int i = 0; i < NPAIR; ++i) {
            float w0 = (2 * i < H) ? row[2 * i] : 0.f;
            float w1 = (2 * i + 1 < H) ? row[2 * i + 1] : 0.f;
            h2_t v; v[0] = (_Float16)w0; v[1] = (_Float16)w1;
            w[i] = v;
        }
    }
    if (tid < 2 * NPAIR) ((unsigned int*)h_sh)[tid] = 0u;

    float c = 0.f;
    const __half* pb = pre + ((size_t)d * M_TOT + (size_t)b * TT) * G4
                           + gate * H + hidc;

    #define LDP(tt_) ({ int tc_ = ((tt_) < TT) ? (tt_) : (TT - 1);          \
                        int t_  = d ? (TT - 1 - tc_) : tc_;                 \
                        pb[(size_t)t_ * G4]; })

    __half p0 = LDP(0), p1 = LDP(1);
    __syncthreads();

    #define STEP(TTT, PJ, BUF) {                                            \
        int t = d ? (TT - 1 - (TTT)) : (TTT);                               \
        float pc = __half2float(PJ);                                        \
        PJ = LDP((TTT) + 2);             /* 2-steps-ahead prefetch */       \
        float a0 = 0.f, a1 = 0.f, a2 = 0.f, a3 = 0.f;                       \
        const uint4* hv = (const uint4*)h_sh[BUF];                          \
        _Pragma("unroll")                                                   \
        for (int i = 0; i < NVEC; ++i) {                                    \
            uint4 hh = hv[i];                                               \
            a0 = dot2f(w[4 * i + 0], bc_h2(hh.x), a0);                      \
            a1 = dot2f(w[4 * i + 1], bc_h2(hh.y), a1);                      \
            a2 = dot2f(w[4 * i + 2], bc_h2(hh.z), a2);                      \
            a3 = dot2f(w[4 * i + 3], bc_h2(hh.w), a3);                      \
        }                                                                   \
        float acc = pc + (a0 + a1) + (a2 + a3);                             \
        float xs = is_g ? (acc + acc) : acc;                                \
        float s = 1.0f / (1.0f + __expf(-xs));                              \
        float act = is_g ? (s + s - 1.0f) : s;                              \
        float fA = dpp_qp<0xB1>(act);     /* gate0 lane <- f (xor1) */      \
        float gA = dpp_qp<0x4E>(act);     /* gate0 lane <- g (xor2) */      \
        float oA = dpp_qp<0x1B>(act);     /* gate0 lane <- o (xor3) */      \
        c = fA * c + act * gA;            /* meaningful in gate0 lanes */   \
        float hval = oA * tanh_f(c);                                        \
        if (writer) {                                                       \
            __half h16 = __float2half(hval);                                \
            hcat[((size_t)b * TT + t) * KLP + (size_t)d * H + hid] = h16;   \
            ((__half*)h_sh[(BUF) ^ 1])[hid] = h16;                          \
        }                                                                   \
        bar_lds();                                                          \
    }

    for (int base = 0; base < TT; base += 2) {
        STEP(base,     p0, 0)
        STEP(base + 1, p1, 1)
    }
    #undef STEP
    #undef LDP
}

extern "C" void kernel_launch(void* const* d_in, const int* in_sizes, int n_in,
                              void* d_out, int out_size, void* d_ws, size_t ws_size,
                              hipStream_t stream) {
    const float* x = (const float*)d_in[0];

    char* ws = (char*)d_ws;
    __half* pre    = (__half*)ws;                                     // 82.4 MB
    __half* hcat16 = (__half*)(ws + (size_t)2 * M_TOT * G4 * 2);      // 22.5 MB
    __half* A16    = (__half*)((char*)hcat16 + (size_t)M_TOT * KLP * 2); // 12.3 MB
    __half* wih3   = (__half*)((char*)A16 + (size_t)M_TOT * KXP * 2);    // 1.55 MB
    __half* W3     = (__half*)((char*)wih3 + (size_t)3 * NWIH * KXP * 2);// 0.41 MB
    float*  bufA   = (float*)((char*)W3 + (size_t)3 * 192 * KLP * 2);    // 20.6 MB
    float*  bufB   = bufA + (size_t)M_TOT * H;                           // 20.6 MB

    const float* const* p0 = (const float* const*)(d_in + 1);
    const float* const* p1 = (const float* const*)(d_in + 11);
    const float* const* p2 = (const float* const*)(d_in + 21);
    // each p: wih_f whh_f bih_f bhh_f wih_b whh_b bih_b bhh_b W bl

    hipMemsetAsync(hcat16, 0, (size_t)M_TOT * KLP * sizeof(__half), stream);
    cvt_x<<<2048, 256, 0, stream>>>(x, A16);
    cvt_wih3<<<dim3(256, 3), 256, 0, stream>>>(
        p0[0], p0[4], p0[2], p0[3], p0[6], p0[7],
        p1[0], p1[4], p1[2], p1[3], p1[6], p1[7],
        p2[0], p2[4], p2[2], p2[3], p2[6], p2[7], wih3);
    cvt_W3<<<dim3(64, 3), 256, 0, stream>>>(p0[8], p1[8], p2[8], W3);

    const float* const* ps[3] = {p0, p1, p2};
    const float* cur = x;
    float* outs[3] = {bufA, bufB, (float*)d_out};

    for (int l = 0; l < 3; ++l) {
        const float* const* p = ps[l];
        pre_mfma<<<dim3(M_TOT / 64, 7), 256, 0, stream>>>(
            A16, wih3 + (size_t)l * NWIH * KXP, pre);
        lstm_scan<<<dim3(32, 2), 704, 0, stream>>>(pre, p[1], p[5], hcat16);
        lin_mfma<<<dim3(M_TOT / 64, 3), 256, 0, stream>>>(
            hcat16, W3 + (size_t)l * 192 * KLP, p[9], cur, outs[l], A16,
            (l < 2) ? 1 : 0, (l < 2) ? 1 : 0);
        cur = outs[l];
    }
}

// Round 15
// 3291.543 us; speedup vs baseline: 1.0656x; 1.0656x over previous
//
#include <hip/hip_runtime.h>
#include <hip/hip_fp16.h>

#define H 161
#define G4 644            // 4*H gates
#define BB 32             // batch
#define TT 1000           // time
#define M_TOT (BB*TT)     // 32000 rows
#define KXP 192           // padded K for pre GEMM (161 data + 1 bias + pad0)
#define KLP 352           // padded K for lin GEMM (322 data + pad0)
#define NWIH 1344         // padded N of wih16 (21 * 64)
#define QD 42             // data halves per k-quarter (4*42 = 168 >= 161)
#define QH 48             // padded quarter stride in halves (96 B, 16B-aligned)
#define QP 21             // half2 pairs per quarter (weights, unpadded)

typedef _Float16 h2_t  __attribute__((ext_vector_type(2)));
typedef _Float16 f16x8 __attribute__((ext_vector_type(8)));
typedef float    f32x4 __attribute__((ext_vector_type(4)));

__device__ __forceinline__ h2_t bc_h2(unsigned int u) {
    return __builtin_bit_cast(h2_t, u);
}

__device__ __forceinline__ float dot2f(h2_t a, h2_t b, float c) {
#if __has_builtin(__builtin_amdgcn_fdot2)
    return __builtin_amdgcn_fdot2(a, b, c, false);
#else
    return c + (float)a[0] * (float)b[0] + (float)a[1] * (float)b[1];
#endif
}

__device__ __forceinline__ float tanh_f(float x) {
    return 1.0f - 2.0f / (__expf(2.0f * x) + 1.0f);
}

// Quad-perm DPP move (returns permuted value). 0xB1=[1,0,3,2], 0x4E=[2,3,0,1],
// 0x1B=[3,2,1,0]. Verified numerically in rounds 2 and 14.
template<int CTRL>
__device__ __forceinline__ float dpp_qp(float x) {
    int y = __builtin_amdgcn_update_dpp(0, __builtin_bit_cast(int, x),
                                        CTRL, 0xF, 0xF, true);
    return __builtin_bit_cast(float, y);
}
// In-quad butterfly add (round-2-verified qsum).
template<int CTRL>
__device__ __forceinline__ float dpp_addf(float x) {
    int y = __builtin_amdgcn_update_dpp(0, __builtin_bit_cast(int, x),
                                        CTRL, 0xF, 0xF, true);
    return x + __builtin_bit_cast(float, y);
}
__device__ __forceinline__ float qsum(float x) {
    x = dpp_addf<0xB1>(x);
    x = dpp_addf<0x4E>(x);
    return x;
}

// Barrier draining only LDS (lgkmcnt), not vmcnt.
__device__ __forceinline__ void bar_lds() {
    __builtin_amdgcn_sched_barrier(0);
    asm volatile("s_waitcnt lgkmcnt(0)" ::: "memory");
    __builtin_amdgcn_s_barrier();
    __builtin_amdgcn_sched_barrier(0);
}

// ---------------------------------------------------------------------------
// cvt_x / cvt_wih3 / cvt_W3 (unchanged from round 13 -- verified).
// ---------------------------------------------------------------------------
__global__ __launch_bounds__(256) void cvt_x(
    const float* __restrict__ in, __half* __restrict__ out)
{
    const int total = M_TOT * KXP;
    for (int idx = blockIdx.x * 256 + threadIdx.x; idx < total;
         idx += gridDim.x * 256) {
        int m = idx / KXP, k = idx - m * KXP;
        float v = (k < H) ? in[(size_t)m * H + k] : (k == H ? 1.f : 0.f);
        out[idx] = __float2half(v);
    }
}

__global__ __launch_bounds__(256) void cvt_wih3(
    const float* __restrict__ wf0, const float* __restrict__ wb0,
    const float* __restrict__ bif0, const float* __restrict__ bhf0,
    const float* __restrict__ bib0, const float* __restrict__ bhb0,
    const float* __restrict__ wf1, const float* __restrict__ wb1,
    const float* __restrict__ bif1, const float* __restrict__ bhf1,
    const float* __restrict__ bib1, const float* __restrict__ bhb1,
    const float* __restrict__ wf2, const float* __restrict__ wb2,
    const float* __restrict__ bif2, const float* __restrict__ bhf2,
    const float* __restrict__ bib2, const float* __restrict__ bhb2,
    __half* __restrict__ out)        // [3][1344][192] fp16
{
    const int l = blockIdx.y;
    const float* wf  = (l == 0) ? wf0  : (l == 1) ? wf1  : wf2;
    const float* wb  = (l == 0) ? wb0  : (l == 1) ? wb1  : wb2;
    const float* bif = (l == 0) ? bif0 : (l == 1) ? bif1 : bif2;
    const float* bhf = (l == 0) ? bhf0 : (l == 1) ? bhf1 : bhf2;
    const float* bib = (l == 0) ? bib0 : (l == 1) ? bib1 : bib2;
    const float* bhb = (l == 0) ? bhb0 : (l == 1) ? bhb1 : bhb2;
    __half* o = out + (size_t)l * NWIH * KXP;

    const int total = NWIH * KXP;
    for (int idx = blockIdx.x * 256 + threadIdx.x; idx < total;
         idx += gridDim.x * 256) {
        int n = idx / KXP, k = idx - n * KXP;
        float v = 0.f;
        if (n < G4) {
            v = (k < H) ? wf[(size_t)n * H + k]
                        : (k == H ? bif[n] + bhf[n] : 0.f);
        } else if (n < 2 * G4) {
            int g = n - G4;
            v = (k < H) ? wb[(size_t)g * H + k]
                        : (k == H ? bib[g] + bhb[g] : 0.f);
        }
        o[idx] = __float2half(v);
    }
}

__global__ __launch_bounds__(256) void cvt_W3(
    const float* __restrict__ W0, const float* __restrict__ W1,
    const float* __restrict__ W2,
    __half* __restrict__ out)        // [3][192][352] fp16
{
    const int l = blockIdx.y;
    const float* W = (l == 0) ? W0 : (l == 1) ? W1 : W2;
    __half* o = out + (size_t)l * 192 * KLP;

    const int total = 192 * KLP;
    for (int idx = blockIdx.x * 256 + threadIdx.x; idx < total;
         idx += gridDim.x * 256) {
        int n = idx / KLP, k = idx - n * KLP;
        float v = (n < H && k < 2 * H) ? W[(size_t)n * (2 * H) + k] : 0.f;
        o[idx] = __float2half(v);
    }
}

// ---------------------------------------------------------------------------
// pre_mfma (unchanged from round 13 -- verified, A-fragment reuse x3).
// ---------------------------------------------------------------------------
__global__ __launch_bounds__(256) void pre_mfma(
    const __half* __restrict__ A16,    // [M][192]
    const __half* __restrict__ Wih16,  // [1344][192] (one layer)
    __half* __restrict__ pre)          // [2][M_TOT][644]
{
    const int m0 = blockIdx.x * 64;
    const int n0b = blockIdx.y * 192;
    const int tid = threadIdx.x;
    const int wv = tid >> 6, l = tid & 63;
    const int wm = wv & 1, wn = wv >> 1;
    const int cl = l & 15, kg = l >> 4;

    const __half* ap = A16 + (size_t)(m0 + wm * 32 + cl) * KXP + kg * 8;
    f16x8 xa0[6], xa1[6];
    #pragma unroll
    for (int kt = 0; kt < 6; ++kt) {
        xa0[kt] = *(const f16x8*)(ap + kt * 32);
        xa1[kt] = *(const f16x8*)(ap + 16 * KXP + kt * 32);
    }

    for (int nb = 0; nb < 3; ++nb) {
        const int n0 = n0b + nb * 64;
        const __half* wp = Wih16 + (size_t)(n0 + wn * 32 + cl) * KXP + kg * 8;

        f32x4 acc[2][2] = {};
        #pragma unroll
        for (int kt = 0; kt < 6; ++kt) {
            f16x8 w0 = *(const f16x8*)(wp + kt * 32);
            f16x8 w1 = *(const f16x8*)(wp + 16 * KXP + kt * 32);
            acc[0][0] = __builtin_amdgcn_mfma_f32_16x16x32_f16(w0, xa0[kt], acc[0][0], 0, 0, 0);
            acc[0][1] = __builtin_amdgcn_mfma_f32_16x16x32_f16(w0, xa1[kt], acc[0][1], 0, 0, 0);
            acc[1][0] = __builtin_amdgcn_mfma_f32_16x16x32_f16(w1, xa0[kt], acc[1][0], 0, 0, 0);
            acc[1][1] = __builtin_amdgcn_mfma_f32_16x16x32_f16(w1, xa1[kt], acc[1][1], 0, 0, 0);
        }

        #pragma unroll
        for (int sn = 0; sn < 2; ++sn)
            #pragma unroll
            for (int sm = 0; sm < 2; ++sm) {
                int n = n0 + wn * 32 + sn * 16 + kg * 4;
                int m = m0 + wm * 32 + sm * 16 + cl;
                if (n < 2 * G4) {
                    int d = (n >= G4) ? 1 : 0;
                    int g = n - d * G4;
                    __half2 lo, hi;
                    lo.x = __float2half(acc[sn][sm][0]);
                    lo.y = __float2half(acc[sn][sm][1]);
                    hi.x = __float2half(acc[sn][sm][2]);
                    hi.y = __float2half(acc[sn][sm][3]);
                    __half* dst = pre + ((size_t)d * M_TOT + m) * G4 + g;
                    *(__half2*)dst = lo;
                    *(__half2*)(dst + 2) = hi;
                }
            }
    }
}

// ---------------------------------------------------------------------------
// lin_mfma (unchanged from round 13 -- verified, fused A16 write).
// ---------------------------------------------------------------------------
__global__ __launch_bounds__(256) void lin_mfma(
    const __half* __restrict__ Hc,     // [M][352] fp16
    const __half* __restrict__ W16,    // [192][352] (one layer)
    const float* __restrict__ bl,      // [161]
    const float* __restrict__ res,     // [M][161] fp32
    float* __restrict__ out,           // [M][161] fp32
    __half* __restrict__ A16out,       // [M][192] fp16 (next layer's A)
    int relu, int wr_a16)
{
    const int m0 = blockIdx.x * 64, n0 = blockIdx.y * 64;
    const int tid = threadIdx.x;
    const int wv = tid >> 6, l = tid & 63;
    const int wm = wv & 1, wn = wv >> 1;
    const int cl = l & 15, kg = l >> 4;

    const __half* ap = Hc  + (size_t)(m0 + wm * 32 + cl) * KLP + kg * 8;
    const __half* wp = W16 + (size_t)(n0 + wn * 32 + cl) * KLP + kg * 8;

    f32x4 acc[2][2] = {};
    #pragma unroll
    for (int kt = 0; kt < 11; ++kt) {
        f16x8 w0 = *(const f16x8*)(wp + kt * 32);
        f16x8 w1 = *(const f16x8*)(wp + 16 * KLP + kt * 32);
        f16x8 x0 = *(const f16x8*)(ap + kt * 32);
        f16x8 x1 = *(const f16x8*)(ap + 16 * KLP + kt * 32);
        acc[0][0] = __builtin_amdgcn_mfma_f32_16x16x32_f16(w0, x0, acc[0][0], 0, 0, 0);
        acc[0][1] = __builtin_amdgcn_mfma_f32_16x16x32_f16(w0, x1, acc[0][1], 0, 0, 0);
        acc[1][0] = __builtin_amdgcn_mfma_f32_16x16x32_f16(w1, x0, acc[1][0], 0, 0, 0);
        acc[1][1] = __builtin_amdgcn_mfma_f32_16x16x32_f16(w1, x1, acc[1][1], 0, 0, 0);
    }

    #pragma unroll
    for (int sn = 0; sn < 2; ++sn)
        #pragma unroll
        for (int sm = 0; sm < 2; ++sm) {
            int nb = n0 + wn * 32 + sn * 16 + kg * 4;
            int m  = m0 + wm * 32 + sm * 16 + cl;
            #pragma unroll
            for (int r = 0; r < 4; ++r) {
                int n = nb + r;
                if (n < H) {
                    float v = acc[sn][sm][r] + bl[n];
                    if (relu) v = fmaxf(v, 0.f);
                    v += res[(size_t)m * H + n];
                    out[(size_t)m * H + n] = v;
                    if (wr_a16)
                        A16out[(size_t)m * KXP + n] = __float2half(v);
                }
            }
        }
}

// ---------------------------------------------------------------------------
// lstm_scan v15 (quad k-split): 704 thr = 11 waves = 176 quads; quad q owns
// hid q. Lane s of a quad holds k-QUARTER s of all 4 gate rows: w[4][21] =
// 84 packed-half2 VGPRs -- exactly the budget the 995us kernel proved clean
// (round 2's 96-reg version spilled; this is the fix). Each lane reads ONLY
// its quarter from LDS: 5 x ds_read_b128 + 1 x b32 = 5.25 KiB/wave/step vs
// 21 KiB in the broadcast layout -- attacks the measured ~1850 cyc/step LDS
// floor (R14 proved the tail was not the path; traffic is). h stored as 4
// quarters each padded to 48 halves (16B-aligned bases; pads stay zero).
// Quad butterfly (8 DPP-adds, R2-verified) completes all 4 gate sums; lane s
// applies ONE activation (own gate; R2 did 4 -- part of its VALU blowup);
// R14-verified 0xB1/0x4E/0x1B DPP collect to lane 0; lane-local c update;
// one lgkm-only barrier per step (R14-verified double-buffer ordering).
// ---------------------------------------------------------------------------
__global__ __launch_bounds__(704, 3) void lstm_scan(
    const __half* __restrict__ pre,      // [2][M_TOT][G4] gate-major
    const float* __restrict__ whh_f,
    const float* __restrict__ whh_b,
    __half* __restrict__ hcat)           // [M_TOT][KLP] fp16
{
    const int b = blockIdx.x;            // 0..31
    const int d = blockIdx.y;            // 0,1
    const int tid = threadIdx.x;
    const int s = tid & 3;               // k-quarter / own-gate index
    const int q = tid >> 2;              // hid (quad) 0..175
    const int qc = (q < H) ? q : (H - 1);
    const bool writer = (s == 0) && (q < H);
    const bool is_g = (s == 2);
    const float* whh = d ? whh_b : whh_f;

    // h double-buffered, 4 quarters x 48 halves each (pads always zero).
    __shared__ __align__(16) __half h_sh[2][4][QH];   // 768 B

    // Weight quarter s of all 4 gate rows of hid qc: w[g][j] covers
    // k = s*42 + 2j, 2j+1 (zero beyond k=160). 84 VGPRs.
    unsigned int w[4][QP];
    #pragma unroll
    for (int g = 0; g < 4; ++g) {
        const float* row = whh + (size_t)(g * H + qc) * H;
        #pragma unroll
        for (int j = 0; j < QP; ++j) {
            int k = s * QD + 2 * j;
            float w0 = (k < H) ? row[k] : 0.f;
            float w1 = (k + 1 < H) ? row[k + 1] : 0.f;
            h2_t v; v[0] = (_Float16)w0; v[1] = (_Float16)w1;
            w[g][j] = __builtin_bit_cast(unsigned int, v);
        }
    }
    if (tid < 2 * 4 * QH / 2) ((unsigned int*)h_sh)[tid] = 0u;

    // h-write target (lane 0 of quad q): quarter q/42, index q%42.
    const int wqq = qc / QD, wqi = qc - wqq * QD;

    float c = 0.f;
    const __half* pb = pre + ((size_t)d * M_TOT + (size_t)b * TT) * G4
                           + s * H + qc;

    #define LDP(tt_) ({ int tc_ = ((tt_) < TT) ? (tt_) : (TT - 1);          \
                        int t_  = d ? (TT - 1 - tc_) : tc_;                 \
                        pb[(size_t)t_ * G4]; })

    __half p0 = LDP(0), p1 = LDP(1);
    __syncthreads();

    #define STEP(TTT, PJ, BUF) {                                            \
        int t = d ? (TT - 1 - (TTT)) : (TTT);                               \
        float pc = __half2float(PJ);                                        \
        PJ = LDP((TTT) + 2);             /* 2-steps-ahead prefetch */       \
        /* Seed own gate's pre into its accumulator. */                     \
        float ai = (s == 0) ? pc : 0.f;                                     \
        float af = (s == 1) ? pc : 0.f;                                     \
        float ag = (s == 2) ? pc : 0.f;                                     \
        float ao = (s == 3) ? pc : 0.f;                                     \
        const __half* hq = h_sh[BUF][s];                                    \
        const uint4* h4 = (const uint4*)hq;                                 \
        _Pragma("unroll")                                                   \
        for (int j = 0; j < 5; ++j) {                                       \
            uint4 hh = h4[j];                                               \
            h2_t hx = bc_h2(hh.x), hy = bc_h2(hh.y);                        \
            h2_t hz = bc_h2(hh.z), hw = bc_h2(hh.w);                        \
            ai = dot2f(bc_h2(w[0][4*j+0]), hx, ai);                         \
            ai = dot2f(bc_h2(w[0][4*j+1]), hy, ai);                         \
            ai = dot2f(bc_h2(w[0][4*j+2]), hz, ai);                         \
            ai = dot2f(bc_h2(w[0][4*j+3]), hw, ai);                         \
            af = dot2f(bc_h2(w[1][4*j+0]), hx, af);                         \
            af = dot2f(bc_h2(w[1][4*j+1]), hy, af);                         \
            af = dot2f(bc_h2(w[1][4*j+2]), hz, af);                         \
            af = dot2f(bc_h2(w[1][4*j+3]), hw, af);                         \
            ag = dot2f(bc_h2(w[2][4*j+0]), hx, ag);                         \
            ag = dot2f(bc_h2(w[2][4*j+1]), hy, ag);                         \
            ag = dot2f(bc_h2(w[2][4*j+2]), hz, ag);                         \
            ag = dot2f(bc_h2(w[2][4*j+3]), hw, ag);                         \
            ao = dot2f(bc_h2(w[3][4*j+0]), hx, ao);                         \
            ao = dot2f(bc_h2(w[3][4*j+1]), hy, ao);                         \
            ao = dot2f(bc_h2(w[3][4*j+2]), hz, ao);                         \
            ao = dot2f(bc_h2(w[3][4*j+3]), hw, ao);                         \
        }                                                                   \
        {   /* pair 20 (last 2 halves of the quarter) */                    \
            h2_t hl = bc_h2(((const unsigned int*)hq)[20]);                 \
            ai = dot2f(bc_h2(w[0][20]), hl, ai);                            \
            af = dot2f(bc_h2(w[1][20]), hl, af);                            \
            ag = dot2f(bc_h2(w[2][20]), hl, ag);                            \
            ao = dot2f(bc_h2(w[3][20]), hl, ao);                            \
        }                                                                   \
        /* Complete all 4 gate sums across the quad (butterfly). */         \
        ai = qsum(ai); af = qsum(af); ag = qsum(ag); ao = qsum(ao);         \
        /* Lane s activates ITS gate only. */                               \
        float own = (s == 0) ? ai : (s == 1) ? af : (s == 2) ? ag : ao;     \
        float xs = is_g ? (own + own) : own;                                \
        float sg = 1.0f / (1.0f + __expf(-xs));                             \
        float act = is_g ? (sg + sg - 1.0f) : sg;                           \
        /* Collect f,g,o into lane 0 (meaningful there only). */            \
        float fA = dpp_qp<0xB1>(act);                                       \
        float gA = dpp_qp<0x4E>(act);                                       \
        float oA = dpp_qp<0x1B>(act);                                       \
        c = fA * c + act * gA;                                              \
        float hval = oA * tanh_f(c);                                        \
        if (writer) {                                                       \
            __half h16 = __float2half(hval);                                \
            hcat[((size_t)b * TT + t) * KLP + (size_t)d * H + q] = h16;     \
            h_sh[(BUF) ^ 1][wqq][wqi] = h16;                                \
        }                                                                   \
        bar_lds();                                                          \
    }

    for (int base = 0; base < TT; base += 2) {
        STEP(base,     p0, 0)
        STEP(base + 1, p1, 1)
    }
    #undef STEP
    #undef LDP
}

extern "C" void kernel_launch(void* const* d_in, const int* in_sizes, int n_in,
                              void* d_out, int out_size, void* d_ws, size_t ws_size,
                              hipStream_t stream) {
    const float* x = (const float*)d_in[0];

    char* ws = (char*)d_ws;
    __half* pre    = (__half*)ws;                                     // 82.4 MB
    __half* hcat16 = (__half*)(ws + (size_t)2 * M_TOT * G4 * 2);      // 22.5 MB
    __half* A16    = (__half*)((char*)hcat16 + (size_t)M_TOT * KLP * 2); // 12.3 MB
    __half* wih3   = (__half*)((char*)A16 + (size_t)M_TOT * KXP * 2);    // 1.55 MB
    __half* W3     = (__half*)((char*)wih3 + (size_t)3 * NWIH * KXP * 2);// 0.41 MB
    float*  bufA   = (float*)((char*)W3 + (size_t)3 * 192 * KLP * 2);    // 20.6 MB
    float*  bufB   = bufA + (size_t)M_TOT * H;                           // 20.6 MB

    const float* const* p0 = (const float* const*)(d_in + 1);
    const float* const* p1 = (const float* const*)(d_in + 11);
    const float* const* p2 = (const float* const*)(d_in + 21);
    // each p: wih_f whh_f bih_f bhh_f wih_b whh_b bih_b bhh_b W bl

    hipMemsetAsync(hcat16, 0, (size_t)M_TOT * KLP * sizeof(__half), stream);
    cvt_x<<<2048, 256, 0, stream>>>(x, A16);
    cvt_wih3<<<dim3(256, 3), 256, 0, stream>>>(
        p0[0], p0[4], p0[2], p0[3], p0[6], p0[7],
        p1[0], p1[4], p1[2], p1[3], p1[6], p1[7],
        p2[0], p2[4], p2[2], p2[3], p2[6], p2[7], wih3);
    cvt_W3<<<dim3(64, 3), 256, 0, stream>>>(p0[8], p1[8], p2[8], W3);

    const float* const* ps[3] = {p0, p1, p2};
    const float* cur = x;
    float* outs[3] = {bufA, bufB, (float*)d_out};

    for (int l = 0; l < 3; ++l) {
        const float* const* p = ps[l];
        pre_mfma<<<dim3(M_TOT / 64, 7), 256, 0, stream>>>(
            A16, wih3 + (size_t)l * NWIH * KXP, pre);
        lstm_scan<<<dim3(32, 2), 704, 0, stream>>>(pre, p[1], p[5], hcat16);
        lin_mfma<<<dim3(M_TOT / 64, 3), 256, 0, stream>>>(
            hcat16, W3 + (size_t)l * 192 * KLP, p[9], cur, outs[l], A16,
            (l < 2) ? 1 : 0, (l < 2) ? 1 : 0);
        cur = outs[l];
    }
}